// Round 6
// baseline (52.876 us; speedup 1.0000x reference)
//
#include <hip/hip_runtime.h>
#include <hip/hip_bf16.h>

#define B_    2048
#define OBS_  1024
#define A_    512
#define NC    128      // [actor 64 | critic 64] hidden cols

typedef __attribute__((ext_vector_type(8))) short bf16x8;
typedef __attribute__((ext_vector_type(4))) float f32x4;

__device__ __forceinline__ float fast_tanh(float x) {
    return 1.0f - 2.0f / (__expf(2.0f * x) + 1.0f);
}

__device__ __forceinline__ unsigned short rne_bf16(float f) {
    union { float f; unsigned u; } v; v.f = f;
    unsigned u = v.u;
    return (unsigned short)((u + 0x7FFFu + ((u >> 16) & 1u)) >> 16);
}

__device__ __forceinline__ unsigned pack2_bf16(float lo, float hi) {
    return (unsigned)rne_bf16(lo) | ((unsigned)rne_bf16(hi) << 16);
}

__device__ __forceinline__ short to_bf16(float f) {
    __hip_bfloat16 h = __float2bfloat16(f);   // RNE
    return *reinterpret_cast<short*>(&h);
}

// broadcast register value from lane k (compile-time k) via SGPR
#define RL(x, k) __int_as_float(__builtin_amdgcn_readlane(__float_as_int(x), (k)))

// ---------------- Kernel 1: MFMA GEMM, self-contained (no weight prep) -------
// hidden[b][0:64] = tanh(x@W1+b1), hidden[b][64:128] = tanh(x@Wc1+bc1)
// B-fragments gathered directly from fp32 W (8 strided dwords, L2-resident).
__global__ __launch_bounds__(256) void k1_mfma(
        const float* __restrict__ x, const float* __restrict__ W1,
        const float* __restrict__ Wc1, const float* __restrict__ b1,
        const float* __restrict__ bc1, float* __restrict__ hidden) {
    const int tid = threadIdx.x;
    const int w   = tid >> 6;          // wave 0..3
    const int l   = tid & 63;
    const int mb  = blockIdx.x;        // rows mb*16

    const int lm   = l & 15;
    const int g    = l >> 4;
    const int kgrp = g * 8;

    const float* xrow = x + (size_t)(mb * 16 + lm) * OBS_ + kgrp;
    const float* Wsel = (w < 2) ? W1 : Wc1;
    const int   ncol0 = ((32 * w) & 63) + lm;       // W-local col of ntile 2w
    const float* pB0  = Wsel + (size_t)kgrp * 64 + ncol0;
    const float* pB1  = pB0 + 16;

    f32x4 acc0 = {0.f, 0.f, 0.f, 0.f};
    f32x4 acc1 = {0.f, 0.f, 0.f, 0.f};

    #pragma unroll 4
    for (int ks = 0; ks < 32; ++ks) {
        const float4* xp = (const float4*)(xrow + ks * 32);
        float4 a0 = xp[0];
        float4 a1 = xp[1];
        const float* pb0 = pB0 + ks * 2048;
        const float* pb1 = pB1 + ks * 2048;
        bf16x8 av, bv0, bv1;
        av[0] = to_bf16(a0.x); av[1] = to_bf16(a0.y);
        av[2] = to_bf16(a0.z); av[3] = to_bf16(a0.w);
        av[4] = to_bf16(a1.x); av[5] = to_bf16(a1.y);
        av[6] = to_bf16(a1.z); av[7] = to_bf16(a1.w);
        #pragma unroll
        for (int i = 0; i < 8; ++i) bv0[i] = to_bf16(pb0[i * 64]);
        #pragma unroll
        for (int i = 0; i < 8; ++i) bv1[i] = to_bf16(pb1[i * 64]);
        acc0 = __builtin_amdgcn_mfma_f32_16x16x32_bf16(av, bv0, acc0, 0, 0, 0);
        acc1 = __builtin_amdgcn_mfma_f32_16x16x32_bf16(av, bv1, acc1, 0, 0, 0);
    }

    // D layout: col = l&15 (+16*ntile), row = g*4 + j
    const int rbase = mb * 16 + g * 4;
    {
        int col = (2 * w) * 16 + lm;
        float bias = (col < 64) ? b1[col] : bc1[col - 64];
        #pragma unroll
        for (int j = 0; j < 4; ++j)
            hidden[(size_t)(rbase + j) * NC + col] = fast_tanh(acc0[j] + bias);
    }
    {
        int col = (2 * w + 1) * 16 + lm;
        float bias = (col < 64) ? b1[col] : bc1[col - 64];
        #pragma unroll
        for (int j = 0; j < 4; ++j)
            hidden[(size_t)(rbase + j) * NC + col] = fast_tanh(acc1[j] + bias);
    }
}

// ---------------- Kernel 2: per-row fused head, self-contained ----------------
__global__ __launch_bounds__(256) void k2_score(
        const float* __restrict__ hidden,
        const int* __restrict__ action_types, const int* __restrict__ action_counts,
        const int* __restrict__ action, const float* __restrict__ emb,
        const float* __restrict__ We,
        const float* __restrict__ W2, const float* __restrict__ b2,
        const float* __restrict__ Wf, const float* __restrict__ ba,
        const float* __restrict__ Wo, const float* __restrict__ bo,
        const float* __restrict__ Wc2, const float* __restrict__ bc2,
        const float* __restrict__ Wc3, const float* __restrict__ bc3,
        float* __restrict__ out) {
    __shared__ unsigned sW2p[32][64];   // (W2[2kp][h], W2[2kp+1][h])
    __shared__ unsigned sWfp[32][64];
    __shared__ unsigned sWc2p[32][64];
    __shared__ unsigned sVTp[32][64];   // (embWe[t][2hp], embWe[t][2hp+1])
    __shared__ int scnt[4][64];

    const int tid = threadIdx.x;
    #pragma unroll
    for (int i = 0; i < 8; ++i) {
        int idx = tid + i * 256;        // 0..2047
        int rp = idx >> 6, hh = idx & 63;
        sW2p [rp][hh] = pack2_bf16(W2 [(2 * rp) * 64 + hh], W2 [(2 * rp + 1) * 64 + hh]);
        sWfp [rp][hh] = pack2_bf16(Wf [(2 * rp) * 64 + hh], Wf [(2 * rp + 1) * 64 + hh]);
        sWc2p[rp][hh] = pack2_bf16(Wc2[(2 * rp) * 64 + hh], Wc2[(2 * rp + 1) * 64 + hh]);
        float s0 = 0.f, s1 = 0.f;
        #pragma unroll
        for (int e = 0; e < 16; ++e) {
            float ev = emb[hh * 16 + e];           // hh = t here
            s0 += ev * We[e * 64 + 2 * rp];
            s1 += ev * We[e * 64 + 2 * rp + 1];
        }
        sVTp[rp][hh] = pack2_bf16(s0, s1);
    }
    __syncthreads();

    const int lane = tid & 63;
    const int wid  = tid >> 6;
    const int b    = blockIdx.x * 4 + wid;
    int* cptr = scnt[wid];
    cptr[lane] = 0;

    // issue global loads early
    float h1v = hidden[b * NC + lane];
    float c1v = hidden[b * NC + 64 + lane];
    const int* at_row = action_types + (size_t)b * A_;
    const int count = action_counts[b];
    const int base = lane * 8;
    int4 p0 = *reinterpret_cast<const int4*>(at_row + base);
    int4 p1 = *reinterpret_cast<const int4*>(at_row + base + 4);
    const int a_star = action[b];
    const int t_star = at_row[a_star] & 63;

    // feats[h] = tanh(sum_k h1[k]*W2[k][h] + b2[h])
    float f = b2[lane];
    #pragma unroll
    for (int kp = 0; kp < 32; ++kp) {
        unsigned pw = sW2p[kp][lane];
        f += RL(h1v, 2 * kp)     * __uint_as_float(pw << 16);
        f += RL(h1v, 2 * kp + 1) * __uint_as_float(pw & 0xffff0000u);
    }
    f = fast_tanh(f);

    // u[h] = sum_k feats[k]*Wf[k][h] + ba[h]
    float u = ba[lane];
    #pragma unroll
    for (int kp = 0; kp < 32; ++kp) {
        unsigned pw = sWfp[kp][lane];
        u += RL(f, 2 * kp)     * __uint_as_float(pw << 16);
        u += RL(f, 2 * kp + 1) * __uint_as_float(pw & 0xffff0000u);
    }

    // critic: cc = tanh(c1@Wc2+bc2); value = cc.Wc3 + bc3
    float cc = bc2[lane];
    #pragma unroll
    for (int kp = 0; kp < 32; ++kp) {
        unsigned pw = sWc2p[kp][lane];
        cc += RL(c1v, 2 * kp)     * __uint_as_float(pw << 16);
        cc += RL(c1v, 2 * kp + 1) * __uint_as_float(pw & 0xffff0000u);
    }
    cc = fast_tanh(cc);
    float pv = cc * Wc3[lane];
    #pragma unroll
    for (int off = 32; off > 0; off >>= 1) pv += __shfl_xor(pv, off);
    const float value = pv + bc3[0];

    // score-per-type: lane = t
    float s = bo[0];
    #pragma unroll
    for (int hp = 0; hp < 32; ++hp) {
        unsigned pvv = sVTp[hp][lane];
        s += fast_tanh(RL(u, 2 * hp)     + __uint_as_float(pvv << 16))         * Wo[2 * hp];
        s += fast_tanh(RL(u, 2 * hp + 1) + __uint_as_float(pvv & 0xffff0000u)) * Wo[2 * hp + 1];
    }

    // wave-private histogram (no barrier needed)
    if (base + 0 < count) atomicAdd(&cptr[p0.x & 63], 1);
    if (base + 1 < count) atomicAdd(&cptr[p0.y & 63], 1);
    if (base + 2 < count) atomicAdd(&cptr[p0.z & 63], 1);
    if (base + 3 < count) atomicAdd(&cptr[p0.w & 63], 1);
    if (base + 4 < count) atomicAdd(&cptr[p1.x & 63], 1);
    if (base + 5 < count) atomicAdd(&cptr[p1.y & 63], 1);
    if (base + 6 < count) atomicAdd(&cptr[p1.z & 63], 1);
    if (base + 7 < count) atomicAdd(&cptr[p1.w & 63], 1);

    // softmax stats over 64 types weighted by counts
    const int cv = cptr[lane];
    float mval = (cv > 0) ? s : -3.0e38f;
    #pragma unroll
    for (int off = 32; off > 0; off >>= 1) mval = fmaxf(mval, __shfl_xor(mval, off));
    const float e  = (float)cv * __expf(s - mval);
    float se = e, sd = e * s;
    #pragma unroll
    for (int off = 32; off > 0; off >>= 1) {
        se += __shfl_xor(se, off);
        sd += __shfl_xor(sd, off);
    }
    const float logZ    = mval + __logf(se);
    const float entropy = logZ - sd / se;
    const float logp    = __shfl(s, t_star) - logZ;

    if (lane == 0) {
        out[b * 3 + 0] = logp;
        out[b * 3 + 1] = entropy;
        out[b * 3 + 2] = value;
    }
}

extern "C" void kernel_launch(void* const* d_in, const int* in_sizes, int n_in,
                              void* d_out, int out_size, void* d_ws, size_t ws_size,
                              hipStream_t stream) {
    const float* x             = (const float*)d_in[0];
    const int*   action_types  = (const int*)  d_in[1];
    const int*   action_counts = (const int*)  d_in[2];
    const int*   action        = (const int*)  d_in[3];
    const float* emb           = (const float*)d_in[4];
    const float* W1            = (const float*)d_in[5];
    const float* b1            = (const float*)d_in[6];
    const float* W2            = (const float*)d_in[7];
    const float* b2            = (const float*)d_in[8];
    const float* Wf            = (const float*)d_in[9];
    const float* We            = (const float*)d_in[10];
    const float* ba            = (const float*)d_in[11];
    const float* Wo            = (const float*)d_in[12];
    const float* bo            = (const float*)d_in[13];
    const float* Wc1           = (const float*)d_in[14];
    const float* bc1           = (const float*)d_in[15];
    const float* Wc2           = (const float*)d_in[16];
    const float* bc2           = (const float*)d_in[17];
    const float* Wc3           = (const float*)d_in[18];
    const float* bc3           = (const float*)d_in[19];
    float* out = (float*)d_out;

    float* hidden = (float*)d_ws;   // 2048*128 f32 = 1 MB

    k1_mfma<<<128, 256, 0, stream>>>(x, W1, Wc1, b1, bc1, hidden);
    k2_score<<<512, 256, 0, stream>>>(hidden, action_types, action_counts, action,
                                      emb, We, W2, b2, Wf, ba, Wo, bo,
                                      Wc2, bc2, Wc3, bc3, out);
}

// Round 7
// 28.877 us; speedup vs baseline: 1.8311x; 1.8311x over previous
//
#include <hip/hip_runtime.h>
#include <hip/hip_bf16.h>

#define B_    2048
#define OBS_  1024
#define A_    512
#define NC    128      // [actor 64 | critic 64] hidden cols

typedef __attribute__((ext_vector_type(8))) short bf16x8;
typedef __attribute__((ext_vector_type(4))) float f32x4;

__device__ __forceinline__ float fast_tanh(float x) {
    return 1.0f - 2.0f / (__expf(2.0f * x) + 1.0f);
}

__device__ __forceinline__ unsigned short rne_bf16(float f) {
    union { float f; unsigned u; } v; v.f = f;
    unsigned u = v.u;
    return (unsigned short)((u + 0x7FFFu + ((u >> 16) & 1u)) >> 16);
}

__device__ __forceinline__ unsigned pack_bf16(float lo, float hi) {
    return (unsigned)rne_bf16(lo) | ((unsigned)rne_bf16(hi) << 16);
}

__device__ __forceinline__ short to_bf16(float f) {
    __hip_bfloat16 h = __float2bfloat16(f);   // RNE
    return *reinterpret_cast<short*>(&h);
}

// broadcast register value from lane k (compile-time k) via SGPR, no LDS
#define RL(x, k) __int_as_float(__builtin_amdgcn_readlane(__float_as_int(x), (k)))

// ---------------- Kernel 0: weight prep ---------------------------------------
// Wfrag: bf16 fragment-major [kstep(32)][ntile(8)][lane(64)][i(8)]
//   k = kstep*32 + (lane>>4)*8 + i, n = ntile*16 + (lane&15)
// embWeT: [h(64)][t(64)] = sum_e emb[t][e] * We[e][h]
__global__ __launch_bounds__(256) void k0_prep(
        const float* __restrict__ W1, const float* __restrict__ Wc1,
        const float* __restrict__ emb, const float* __restrict__ We,
        unsigned short* __restrict__ Wfrag, float* __restrict__ embWeT) {
    const int bid = blockIdx.x, tid = threadIdx.x;
    if (bid < 512) {
        int gid   = bid * 256 + tid;
        int i     = gid & 7;
        int lane  = (gid >> 3) & 63;
        int ntile = (gid >> 9) & 7;
        int ks    = gid >> 12;
        int k = ks * 32 + ((lane >> 4) << 3) + i;
        int n = ntile * 16 + (lane & 15);
        float w = (n < 64) ? W1[(size_t)k * 64 + n] : Wc1[(size_t)k * 64 + (n - 64)];
        Wfrag[gid] = rne_bf16(w);
    } else {
        int idx = (bid - 512) * 256 + tid;
        int h = idx >> 6, t = idx & 63;
        float s = 0.f;
        #pragma unroll
        for (int e = 0; e < 16; ++e) s += emb[t * 16 + e] * We[e * 64 + h];
        embWeT[idx] = s;
    }
}

// ---------------- Kernel 1: MFMA bf16 GEMM, barrier-free 4-way K-split --------
// grid 512: mb = bid>>2 (16-row tile), kslice = bid&3 (256 K each)
// partials[kslice][row][col] fp32; bias+tanh deferred to k2.
__global__ __launch_bounds__(256) void k1_mfma(
        const float* __restrict__ x, const unsigned short* __restrict__ Wfrag,
        float* __restrict__ partials) {
    const int tid = threadIdx.x;
    const int w   = tid >> 6;
    const int l   = tid & 63;
    const int mb     = blockIdx.x >> 2;
    const int kslice = blockIdx.x & 3;

    const int row  = mb * 16 + (l & 15);
    const int kgrp = (l >> 4) << 3;
    const float* xrow = x + (size_t)row * OBS_ + kslice * 256;
    const bf16x8* Wf8 = (const bf16x8*)Wfrag;

    f32x4 acc0 = {0.f, 0.f, 0.f, 0.f};
    f32x4 acc1 = {0.f, 0.f, 0.f, 0.f};
    const int nt0 = w * 2, nt1 = w * 2 + 1;

    #pragma unroll
    for (int ks = 0; ks < 8; ++ks) {
        const float4* xp = (const float4*)(xrow + ks * 32 + kgrp);
        float4 a0 = xp[0];
        float4 a1 = xp[1];
        bf16x8 av;
        av[0] = to_bf16(a0.x); av[1] = to_bf16(a0.y);
        av[2] = to_bf16(a0.z); av[3] = to_bf16(a0.w);
        av[4] = to_bf16(a1.x); av[5] = to_bf16(a1.y);
        av[6] = to_bf16(a1.z); av[7] = to_bf16(a1.w);
        const int kg = kslice * 8 + ks;
        bf16x8 bv0 = Wf8[(kg * 8 + nt0) * 64 + l];
        bf16x8 bv1 = Wf8[(kg * 8 + nt1) * 64 + l];
        acc0 = __builtin_amdgcn_mfma_f32_16x16x32_bf16(av, bv0, acc0, 0, 0, 0);
        acc1 = __builtin_amdgcn_mfma_f32_16x16x32_bf16(av, bv1, acc1, 0, 0, 0);
    }

    // C/D layout: col = lane&15, row = (lane>>4)*4 + reg
    float* pbase = partials + (size_t)kslice * B_ * NC;
    const int rbase = mb * 16 + ((l >> 4) << 2);
    {
        int col = nt0 * 16 + (l & 15);
        #pragma unroll
        for (int r = 0; r < 4; ++r)
            pbase[(size_t)(rbase + r) * NC + col] = acc0[r];
    }
    {
        int col = nt1 * 16 + (l & 15);
        #pragma unroll
        for (int r = 0; r < 4; ++r)
            pbase[(size_t)(rbase + r) * NC + col] = acc1[r];
    }
}

// ---------------- Kernel 2: per-row fused head (1 wave = 1 batch row) ---------
__global__ __launch_bounds__(256) void k2_score(
        const float* __restrict__ partials, const float* __restrict__ embWeT,
        const int* __restrict__ action_types, const int* __restrict__ action_counts,
        const int* __restrict__ action,
        const float* __restrict__ b1, const float* __restrict__ bc1,
        const float* __restrict__ W2, const float* __restrict__ b2,
        const float* __restrict__ Wf,
        const float* __restrict__ ba, const float* __restrict__ Wo,
        const float* __restrict__ bo, const float* __restrict__ Wc2,
        const float* __restrict__ bc2, const float* __restrict__ Wc3,
        const float* __restrict__ bc3, float* __restrict__ out) {
    // bf16x2-packed weights: [kp][h] holds (W[2kp][h], W[2kp+1][h])
    __shared__ unsigned sW2p[32][64];
    __shared__ unsigned sWfp[32][64];
    __shared__ unsigned sWc2p[32][64];
    __shared__ unsigned sVTp[32][64];   // (embWeT[2hp][t], embWeT[2hp+1][t])
    __shared__ int scnt[4][64];

    const int tid = threadIdx.x;
    #pragma unroll
    for (int i = 0; i < 8; ++i) {
        int idx = tid + i * 256;        // 0..2047
        int rp = idx >> 6, hh = idx & 63;
        sW2p [rp][hh] = pack_bf16(W2 [(2 * rp) * 64 + hh], W2 [(2 * rp + 1) * 64 + hh]);
        sWfp [rp][hh] = pack_bf16(Wf [(2 * rp) * 64 + hh], Wf [(2 * rp + 1) * 64 + hh]);
        sWc2p[rp][hh] = pack_bf16(Wc2[(2 * rp) * 64 + hh], Wc2[(2 * rp + 1) * 64 + hh]);
        sVTp [rp][hh] = pack_bf16(embWeT[(2 * rp) * 64 + hh], embWeT[(2 * rp + 1) * 64 + hh]);
    }
    scnt[tid >> 6][tid & 63] = 0;
    __syncthreads();

    const int lane = tid & 63;
    const int wid  = tid >> 6;
    const int b    = blockIdx.x * 4 + wid;

    // issue global loads early: 4 K-split partials for actor/critic + action data
    const float* pa = partials + (size_t)b * NC + lane;
    const float* pc = pa + 64;
    float h1v = pa[0] + pa[1 * B_ * NC] + pa[2 * B_ * NC] + pa[3 * B_ * NC];
    float c1v = pc[0] + pc[1 * B_ * NC] + pc[2 * B_ * NC] + pc[3 * B_ * NC];
    h1v = fast_tanh(h1v + b1[lane]);
    c1v = fast_tanh(c1v + bc1[lane]);
    const int* at_row = action_types + (size_t)b * A_;
    const int count = action_counts[b];
    const int base = lane * 8;
    int4 p0 = *reinterpret_cast<const int4*>(at_row + base);
    int4 p1 = *reinterpret_cast<const int4*>(at_row + base + 4);
    const int a_star = action[b];
    const int t_star = at_row[a_star] & 63;

    // feats[h] = tanh(sum_k h1[k]*W2[k][h] + b2[h])
    float f = b2[lane];
    #pragma unroll
    for (int kp = 0; kp < 32; ++kp) {
        unsigned pw = sW2p[kp][lane];
        f += RL(h1v, 2 * kp)     * __uint_as_float(pw << 16);
        f += RL(h1v, 2 * kp + 1) * __uint_as_float(pw & 0xffff0000u);
    }
    f = fast_tanh(f);

    // u[h] = sum_k feats[k]*Wf[k][h] + ba[h]
    float u = ba[lane];
    #pragma unroll
    for (int kp = 0; kp < 32; ++kp) {
        unsigned pw = sWfp[kp][lane];
        u += RL(f, 2 * kp)     * __uint_as_float(pw << 16);
        u += RL(f, 2 * kp + 1) * __uint_as_float(pw & 0xffff0000u);
    }

    // critic: cc = tanh(c1@Wc2+bc2); value = cc.Wc3 + bc3
    float cc = bc2[lane];
    #pragma unroll
    for (int kp = 0; kp < 32; ++kp) {
        unsigned pw = sWc2p[kp][lane];
        cc += RL(c1v, 2 * kp)     * __uint_as_float(pw << 16);
        cc += RL(c1v, 2 * kp + 1) * __uint_as_float(pw & 0xffff0000u);
    }
    cc = fast_tanh(cc);
    float pv = cc * Wc3[lane];
    #pragma unroll
    for (int off = 32; off > 0; off >>= 1) pv += __shfl_xor(pv, off);
    const float value = pv + bc3[0];

    // score-per-type: lane = t
    float s = bo[0];
    #pragma unroll
    for (int hp = 0; hp < 32; ++hp) {
        unsigned pvv = sVTp[hp][lane];
        s += fast_tanh(RL(u, 2 * hp)     + __uint_as_float(pvv << 16))         * Wo[2 * hp];
        s += fast_tanh(RL(u, 2 * hp + 1) + __uint_as_float(pvv & 0xffff0000u)) * Wo[2 * hp + 1];
    }

    // histogram of valid action types (wave-private)
    int* cptr = scnt[wid];
    if (base + 0 < count) atomicAdd(&cptr[p0.x & 63], 1);
    if (base + 1 < count) atomicAdd(&cptr[p0.y & 63], 1);
    if (base + 2 < count) atomicAdd(&cptr[p0.z & 63], 1);
    if (base + 3 < count) atomicAdd(&cptr[p0.w & 63], 1);
    if (base + 4 < count) atomicAdd(&cptr[p1.x & 63], 1);
    if (base + 5 < count) atomicAdd(&cptr[p1.y & 63], 1);
    if (base + 6 < count) atomicAdd(&cptr[p1.z & 63], 1);
    if (base + 7 < count) atomicAdd(&cptr[p1.w & 63], 1);

    // softmax stats over 64 types weighted by counts
    const int cv = cptr[lane];
    float mval = (cv > 0) ? s : -3.0e38f;
    #pragma unroll
    for (int off = 32; off > 0; off >>= 1) mval = fmaxf(mval, __shfl_xor(mval, off));
    const float e  = (float)cv * __expf(s - mval);
    float se = e, sd = e * s;
    #pragma unroll
    for (int off = 32; off > 0; off >>= 1) {
        se += __shfl_xor(se, off);
        sd += __shfl_xor(sd, off);
    }
    const float logZ    = mval + __logf(se);
    const float entropy = logZ - sd / se;
    const float logp    = __shfl(s, t_star) - logZ;

    if (lane == 0) {
        out[b * 3 + 0] = logp;
        out[b * 3 + 1] = entropy;
        out[b * 3 + 2] = value;
    }
}

extern "C" void kernel_launch(void* const* d_in, const int* in_sizes, int n_in,
                              void* d_out, int out_size, void* d_ws, size_t ws_size,
                              hipStream_t stream) {
    const float* x             = (const float*)d_in[0];
    const int*   action_types  = (const int*)  d_in[1];
    const int*   action_counts = (const int*)  d_in[2];
    const int*   action        = (const int*)  d_in[3];
    const float* emb           = (const float*)d_in[4];
    const float* W1            = (const float*)d_in[5];
    const float* b1            = (const float*)d_in[6];
    const float* W2            = (const float*)d_in[7];
    const float* b2            = (const float*)d_in[8];
    const float* Wf            = (const float*)d_in[9];
    const float* We            = (const float*)d_in[10];
    const float* ba            = (const float*)d_in[11];
    const float* Wo            = (const float*)d_in[12];
    const float* bo            = (const float*)d_in[13];
    const float* Wc1           = (const float*)d_in[14];
    const float* bc1           = (const float*)d_in[15];
    const float* Wc2           = (const float*)d_in[16];
    const float* bc2           = (const float*)d_in[17];
    const float* Wc3           = (const float*)d_in[18];
    const float* bc3           = (const float*)d_in[19];
    float* out = (float*)d_out;

    unsigned char* ws = (unsigned char*)d_ws;
    unsigned short* Wfrag  = (unsigned short*)ws;            // 256 KB
    float*          embWeT = (float*)(ws + 262144);          // 16 KB
    float*          partials = (float*)(ws + 262144 + 16384); // 4 MB (4 x 2048 x 128)

    k0_prep<<<528, 256, 0, stream>>>(W1, Wc1, emb, We, Wfrag, embWeT);
    k1_mfma<<<512, 256, 0, stream>>>(x, Wfrag, partials);
    k2_score<<<512, 256, 0, stream>>>(partials, embWeT, action_types, action_counts,
                                      action, b1, bc1, W2, b2, Wf, ba, Wo, bo,
                                      Wc2, bc2, Wc3, bc3, out);
}